// Round 3
// baseline (306.634 us; speedup 1.0000x reference)
//
#include <hip/hip_runtime.h>
#include <math.h>

typedef __attribute__((ext_vector_type(8))) short short8;
typedef __attribute__((ext_vector_type(4))) float f32x4;

#define NTOK 32768          // B*L
#define DDIM 1024
#define HDIM 64
#define NB 16
#define LN_EPS 1e-5f

#define IDX_OFF ((size_t)NTOK * NB)            // 524288
#define AUX_OFF (IDX_OFF + (size_t)NTOK * 2)   // 589824
#define WT_OFF  (AUX_OFF + 1)                  // 589825

// ws float layout:
//   [0:64)    csg = colsum(gamma*W1)
//   [64:128)  csb = colsum(beta*W1)
//   [256 : 256+98304)  B-pack: 3 terms x 32 ksteps x 4 ntiles x 64 lanes x 4 dwords
//   [98560 : 98560+65536)  per-wave partials: 2048 waves x [0:16 cnt | 16:32 Psum]
#define BP_F   256
#define PART_F 98560

__device__ __forceinline__ short8 as_s8(uint4 u) {
    union { uint4 u; short8 s; } x; x.u = u; return x.s;
}

__global__ void colsum_kernel(const float* __restrict__ W1,
                              const float* __restrict__ gamma,
                              const float* __restrict__ beta,
                              float* __restrict__ ws) {
    __shared__ float sg[4][64];
    __shared__ float sb[4][64];
    const int t = threadIdx.x;          // 256
    const int j = t & 63;
    const int part = t >> 6;
    const int d0 = blockIdx.x * 64 + part * 16;
    float ag = 0.f, ab = 0.f;
    for (int dd = 0; dd < 16; ++dd) {
        const int d = d0 + dd;
        const float w = W1[d * HDIM + j];
        ag += gamma[d] * w;
        ab += beta[d] * w;
    }
    sg[part][j] = ag;
    sb[part][j] = ab;
    __syncthreads();
    if (t < 64) {
        atomicAdd(&ws[t],      sg[0][t] + sg[1][t] + sg[2][t] + sg[3][t]);
        atomicAdd(&ws[64 + t], sb[0][t] + sb[1][t] + sb[2][t] + sb[3][t]);
    }
}

// Pre-pack gamma*W1 into MFMA B-fragment order, 3-term bf16 split.
// Frag convention (16x16x32): lane l holds B[k = 32s + 8*(l>>4) + j][n16 + (l&15)], j=0..7.
__global__ void pack_kernel(const float* __restrict__ W1,
                            const float* __restrict__ gamma,
                            unsigned int* __restrict__ bp) {
    const int s = blockIdx.x;           // 0..31 k-step
    const int t = threadIdx.x;          // 256
    const int n = t >> 6;               // n-tile 0..3
    const int l = t & 63;               // frag lane
    const int q = l >> 4, c = l & 15;
    const int col = n * 16 + c;
    unsigned int uh[8], um[8], ul[8];
#pragma unroll
    for (int j = 0; j < 8; ++j) {
        const int k = s * 32 + q * 8 + j;
        const float w = gamma[k] * W1[k * HDIM + col];
        const unsigned int b  = __float_as_uint(w);
        const unsigned int hb = b & 0xFFFF0000u;
        const float r  = w - __uint_as_float(hb);
        const unsigned int mb = __float_as_uint(r) & 0xFFFF0000u;
        const float r2 = r - __uint_as_float(mb);
        const unsigned int lb = __float_as_uint(r2) & 0xFFFF0000u;
        uh[j] = hb >> 16; um[j] = mb >> 16; ul[j] = lb >> 16;
    }
    const int base = ((s * 4 + n) * 64 + l) * 4;
#pragma unroll
    for (int d = 0; d < 4; ++d) {
        bp[base + d]         = uh[2 * d] | (uh[2 * d + 1] << 16);
        bp[32768 + base + d] = um[2 * d] | (um[2 * d + 1] << 16);
        bp[65536 + base + d] = ul[2 * d] | (ul[2 * d + 1] << 16);
    }
}

__global__ __launch_bounds__(256, 2)
void router_main(const float* __restrict__ x,
                 const float* __restrict__ ws,          // csg/csb
                 const unsigned int* __restrict__ bp,   // packed B frags
                 const float* __restrict__ W2,
                 float* __restrict__ part,
                 float* __restrict__ out) {
    __shared__ float ylds[4][16][68];   // per-wave private h scratch

    const int t    = threadIdx.x;
    const int wv   = t >> 6;
    const int lane = t & 63;
    const int q = lane >> 4, c = lane & 15;
    const int tok0 = blockIdx.x * 64 + wv * 16;   // this wave's 16 tokens

    const float* xrow = x + (size_t)(tok0 + c) * DDIM + q * 8;
    const unsigned int* bpl = bp + lane * 4;

    f32x4 acc[4] = {{0.f,0.f,0.f,0.f},{0.f,0.f,0.f,0.f},{0.f,0.f,0.f,0.f},{0.f,0.f,0.f,0.f}};
    float s1 = 0.f, s2 = 0.f;

    float4 ra0 = *(const float4*)xrow;
    float4 ra1 = *(const float4*)(xrow + 4);

    for (int s = 0; s < 32; ++s) {
        // B frags for this k-step (L2-resident, shared by all blocks)
        uint4 bh[4], bm[4], bl[4];
#pragma unroll
        for (int n = 0; n < 4; ++n) {
            bh[n] = *(const uint4*)(bpl + (s * 4 + n) * 256);
            bm[n] = *(const uint4*)(bpl + 32768 + (s * 4 + n) * 256);
            bl[n] = *(const uint4*)(bpl + 65536 + (s * 4 + n) * 256);
        }
        // A prefetch next k-step (HBM)
        const int sn = (s + 1) & 31;
        const float4 na0 = *(const float4*)(xrow + sn * 32);
        const float4 na1 = *(const float4*)(xrow + sn * 32 + 4);

        // split raw x into 3 truncated-bf16 terms + LN stats
        const float v[8] = {ra0.x, ra0.y, ra0.z, ra0.w, ra1.x, ra1.y, ra1.z, ra1.w};
        unsigned int ph[4], pm[4], pl[4];
#pragma unroll
        for (int d = 0; d < 4; ++d) {
            const float v0 = v[2 * d], v1 = v[2 * d + 1];
            const unsigned int h0 = __float_as_uint(v0) & 0xFFFF0000u;
            const unsigned int h1 = __float_as_uint(v1) & 0xFFFF0000u;
            const float r0 = v0 - __uint_as_float(h0);
            const float r1 = v1 - __uint_as_float(h1);
            const unsigned int m0 = __float_as_uint(r0) & 0xFFFF0000u;
            const unsigned int m1 = __float_as_uint(r1) & 0xFFFF0000u;
            const float q0 = r0 - __uint_as_float(m0);
            const float q1 = r1 - __uint_as_float(m1);
            ph[d] = (h0 >> 16) | h1;
            pm[d] = (m0 >> 16) | m1;
            pl[d] = (__float_as_uint(q0) >> 16) | (__float_as_uint(q1) & 0xFFFF0000u);
            s1 += v0 + v1;
            s2 = fmaf(v0, v0, fmaf(v1, v1, s2));
        }
        const short8 AH = as_s8(make_uint4(ph[0], ph[1], ph[2], ph[3]));
        const short8 AM = as_s8(make_uint4(pm[0], pm[1], pm[2], pm[3]));
        const short8 AL = as_s8(make_uint4(pl[0], pl[1], pl[2], pl[3]));

#pragma unroll
        for (int n = 0; n < 4; ++n) {
            acc[n] = __builtin_amdgcn_mfma_f32_16x16x32_bf16(AH, as_s8(bh[n]), acc[n], 0, 0, 0);
            acc[n] = __builtin_amdgcn_mfma_f32_16x16x32_bf16(AH, as_s8(bm[n]), acc[n], 0, 0, 0);
            acc[n] = __builtin_amdgcn_mfma_f32_16x16x32_bf16(AM, as_s8(bh[n]), acc[n], 0, 0, 0);
            acc[n] = __builtin_amdgcn_mfma_f32_16x16x32_bf16(AH, as_s8(bl[n]), acc[n], 0, 0, 0);
            acc[n] = __builtin_amdgcn_mfma_f32_16x16x32_bf16(AM, as_s8(bm[n]), acc[n], 0, 0, 0);
            acc[n] = __builtin_amdgcn_mfma_f32_16x16x32_bf16(AL, as_s8(bh[n]), acc[n], 0, 0, 0);
        }
        ra0 = na0; ra1 = na1;
    }

    // LN stats: lane's partial covers token tok0+c, k in {32s+8q+j}; sum over q-lanes
    s1 += __shfl_xor(s1, 16, 64); s1 += __shfl_xor(s1, 32, 64);
    s2 += __shfl_xor(s2, 16, 64); s2 += __shfl_xor(s2, 32, 64);
    // now lane holds stats for token tok0+c (c = lane&15)

    float csg[4], csb[4];
#pragma unroll
    for (int n = 0; n < 4; ++n) {
        csg[n] = ws[n * 16 + c];
        csb[n] = ws[64 + n * 16 + c];
    }

    // C/D layout: row(token-in-wave) = q*4 + r, col = n*16 + c
#pragma unroll
    for (int r = 0; r < 4; ++r) {
        const float S1 = __shfl(s1, q * 4 + r, 64);
        const float S2 = __shfl(s2, q * 4 + r, 64);
        const float mu   = S1 * (1.0f / 1024.0f);
        const float var  = S2 * (1.0f / 1024.0f) - mu * mu;
        const float rstd = 1.0f / sqrtf(var + LN_EPS);
#pragma unroll
        for (int n = 0; n < 4; ++n) {
            const float pre = rstd * (acc[n][r] - mu * csg[n]) + csb[n];
            const float h = 0.5f * pre * (1.0f + erff(pre * 0.70710678118654752f));
            ylds[wv][q * 4 + r][n * 16 + c] = h;
        }
    }
    __syncthreads();

    // logits: lane owns token c, cols q*16..q*16+15; partial W2-dot then q-reduce
    float lp[16];
#pragma unroll
    for (int nb = 0; nb < NB; ++nb) lp[nb] = 0.f;
#pragma unroll
    for (int u = 0; u < 4; ++u) {
        const float4 hv = *(const float4*)&ylds[wv][c][q * 16 + u * 4];
        const float he[4] = {hv.x, hv.y, hv.z, hv.w};
#pragma unroll
        for (int e = 0; e < 4; ++e) {
            const float* w2r = W2 + (size_t)(q * 16 + u * 4 + e) * NB;
#pragma unroll
            for (int nb = 0; nb < NB; ++nb) lp[nb] = fmaf(he[e], w2r[nb], lp[nb]);
        }
    }
#pragma unroll
    for (int nb = 0; nb < NB; ++nb) {
        lp[nb] += __shfl_xor(lp[nb], 16, 64);
        lp[nb] += __shfl_xor(lp[nb], 32, 64);
        lp[nb] *= 0.5f;                                   // /TEMP
    }

    // softmax (every lane has full logits of token tok0+c)
    float mx = -1e30f;
#pragma unroll
    for (int nb = 0; nb < NB; ++nb) mx = fmaxf(mx, lp[nb]);
    float sum = 0.f;
#pragma unroll
    for (int nb = 0; nb < NB; ++nb) { lp[nb] = expf(lp[nb] - mx); sum += lp[nb]; }
    const float inv = 1.0f / sum;
#pragma unroll
    for (int nb = 0; nb < NB; ++nb) lp[nb] *= inv;

    // top-2 (strict >, ties keep lower index)
    float b0 = -1.f, b1 = -1.f;
    int i0 = 0, i1 = 0;
#pragma unroll
    for (int nb = 0; nb < NB; ++nb) {
        if (lp[nb] > b0)      { b1 = b0; i1 = i0; b0 = lp[nb]; i0 = nb; }
        else if (lp[nb] > b1) { b1 = lp[nb]; i1 = nb; }
    }

    if (lane < 16) {   // q==0: one writer per token
        float* po = out + (size_t)(tok0 + c) * NB;
#pragma unroll
        for (int nb = 0; nb < NB; ++nb) po[nb] = lp[nb];
        const float wsum = b0 + b1 + 1e-8f;
        out[IDX_OFF + (size_t)(tok0 + c) * 2]     = (float)i0;
        out[IDX_OFF + (size_t)(tok0 + c) * 2 + 1] = (float)i1;
        out[WT_OFF + (size_t)(tok0 + c) * 2]      = b0 / wsum;
        out[WT_OFF + (size_t)(tok0 + c) * 2 + 1]  = b1 / wsum;
    }

    // per-wave aux partials: counts + prob-sums, reduced over the 16 tokens
    float cnt[16];
#pragma unroll
    for (int nb = 0; nb < NB; ++nb)
        cnt[nb] = (nb == i0 ? 1.f : 0.f) + (nb == i1 ? 1.f : 0.f);
#pragma unroll
    for (int m = 1; m <= 8; m <<= 1) {
#pragma unroll
        for (int nb = 0; nb < NB; ++nb) {
            cnt[nb] += __shfl_xor(cnt[nb], m, 64);
            lp[nb]  += __shfl_xor(lp[nb], m, 64);
        }
    }
    if (lane == 0) {
        float* pw = part + ((size_t)blockIdx.x * 4 + wv) * 32;
#pragma unroll
        for (int nb = 0; nb < NB; ++nb) { pw[nb] = cnt[nb]; pw[16 + nb] = lp[nb]; }
    }
}

__global__ void aux_kernel(const float* __restrict__ part, float* __restrict__ out) {
    __shared__ float red[8][32];
    const int t = threadIdx.x;          // 256
    const int i = t & 31;
    const int g = t >> 5;
    float s = 0.f;
    for (int w = g; w < 2048; w += 8) s += part[(size_t)w * 32 + i];
    red[g][i] = s;
    __syncthreads();
    if (t < 32) {
        float tot = 0.f;
#pragma unroll
        for (int p = 0; p < 8; ++p) tot += red[p][t];
        red[0][t] = tot;
    }
    __syncthreads();
    if (t == 0) {
        float a = 0.f;
        for (int k = 0; k < NB; ++k) {
            const float f = red[0][k] / (65536.0f + 1e-8f);
            const float P = red[0][16 + k] * (1.0f / 32768.0f);
            a += f * P;
        }
        out[AUX_OFF] = 16.0f * a;
    }
}

extern "C" void kernel_launch(void* const* d_in, const int* in_sizes, int n_in,
                              void* d_out, int out_size, void* d_ws, size_t ws_size,
                              hipStream_t stream) {
    const float* x     = (const float*)d_in[0];
    const float* gamma = (const float*)d_in[1];
    const float* beta  = (const float*)d_in[2];
    const float* W1    = (const float*)d_in[3];
    const float* W2    = (const float*)d_in[4];
    float* out = (float*)d_out;
    float* ws  = (float*)d_ws;

    hipMemsetAsync(ws, 0, 128 * sizeof(float), stream);
    colsum_kernel<<<16, 256, 0, stream>>>(W1, gamma, beta, ws);
    pack_kernel<<<32, 256, 0, stream>>>(W1, gamma, (unsigned int*)(ws + BP_F));
    router_main<<<NTOK / 64, 256, 0, stream>>>(x, ws, (const unsigned int*)(ws + BP_F),
                                               W2, ws + PART_F, out);
    aux_kernel<<<1, 256, 0, stream>>>(ws + PART_F, out);
}

// Round 4
// 282.194 us; speedup vs baseline: 1.0866x; 1.0866x over previous
//
#include <hip/hip_runtime.h>
#include <math.h>

typedef __attribute__((ext_vector_type(8))) short short8;
typedef __attribute__((ext_vector_type(4))) float f32x4;

#define NTOK 32768          // B*L
#define DDIM 1024
#define HDIM 64
#define NB 16
#define LN_EPS 1e-5f

#define IDX_OFF ((size_t)NTOK * NB)            // 524288
#define AUX_OFF (IDX_OFF + (size_t)NTOK * 2)   // 589824
#define WT_OFF  (AUX_OFF + 1)                  // 589825

// ws (float) layout:
//   [0:16)   global counts accum      [16:32) global Psum accum
//   [32]     block-completion counter (as uint)
//   [64 : 64+4096)   cs partials: 32 k-ranges x {csg[64], csb[64]}
//   [4352 : +98304)  B-pack: 3 terms x 32 ksteps x 4 ntiles x 64 lanes x 4 dw
#define CS_F 64
#define BP_F 4352

__device__ __forceinline__ short8 as_s8(uint4 u) {
    union { uint4 u; short8 s; } x; x.u = u; return x.s;
}

// Fused: B-pack (3-term bf16 split of gamma*W1, MFMA B-frag order) + per-k-range
// colsum partials of gamma*W1 and beta*W1.
__global__ void pack_kernel(const float* __restrict__ W1,
                            const float* __restrict__ gamma,
                            const float* __restrict__ beta,
                            float* __restrict__ ws) {
    __shared__ float sg[4][64];
    __shared__ float sb[4][64];
    const int s = blockIdx.x;           // k-range 32s..32s+31
    const int t = threadIdx.x;          // 256

    // ---- cs partials ----
    {
        const int j = t & 63, p = t >> 6;
        float ag = 0.f, ab = 0.f;
        for (int kk = 0; kk < 8; ++kk) {
            const int k = s * 32 + p * 8 + kk;
            const float w = W1[k * HDIM + j];
            ag += gamma[k] * w;
            ab += beta[k] * w;
        }
        sg[p][j] = ag;
        sb[p][j] = ab;
    }

    // ---- B pack ----
    {
        unsigned int* bp = (unsigned int*)(ws + BP_F);
        const int n = t >> 6;           // n-tile
        const int l = t & 63;           // frag lane
        const int q = l >> 4, c = l & 15;
        const int col = n * 16 + c;
        unsigned int uh[8], um[8], ul[8];
#pragma unroll
        for (int j = 0; j < 8; ++j) {
            const int k = s * 32 + q * 8 + j;
            const float w = gamma[k] * W1[k * HDIM + col];
            const unsigned int hb = __float_as_uint(w) & 0xFFFF0000u;
            const float r = w - __uint_as_float(hb);
            const unsigned int mb = __float_as_uint(r) & 0xFFFF0000u;
            const float r2 = r - __uint_as_float(mb);
            const unsigned int lb = __float_as_uint(r2) & 0xFFFF0000u;
            uh[j] = hb >> 16; um[j] = mb >> 16; ul[j] = lb >> 16;
        }
        const int base = ((s * 4 + n) * 64 + l) * 4;
#pragma unroll
        for (int d = 0; d < 4; ++d) {
            bp[base + d]         = uh[2 * d] | (uh[2 * d + 1] << 16);
            bp[32768 + base + d] = um[2 * d] | (um[2 * d + 1] << 16);
            bp[65536 + base + d] = ul[2 * d] | (ul[2 * d + 1] << 16);
        }
    }
    __syncthreads();
    if (t < 64) {
        ws[CS_F + s * 128 + t]      = sg[0][t] + sg[1][t] + sg[2][t] + sg[3][t];
        ws[CS_F + s * 128 + 64 + t] = sb[0][t] + sb[1][t] + sb[2][t] + sb[3][t];
    }
}

// 3-term truncated-bf16 split of 8 floats + LN-stat accumulation.
__device__ __forceinline__ void split8(const float4 a0, const float4 a1,
                                       short8& AH, short8& AM, short8& AL,
                                       float& s1, float& s2) {
    const float v[8] = {a0.x, a0.y, a0.z, a0.w, a1.x, a1.y, a1.z, a1.w};
    unsigned int ph[4], pm[4], pl[4];
#pragma unroll
    for (int d = 0; d < 4; ++d) {
        const float v0 = v[2 * d], v1 = v[2 * d + 1];
        const unsigned int h0 = __float_as_uint(v0) & 0xFFFF0000u;
        const unsigned int h1 = __float_as_uint(v1) & 0xFFFF0000u;
        const float r0 = v0 - __uint_as_float(h0);
        const float r1 = v1 - __uint_as_float(h1);
        const unsigned int m0 = __float_as_uint(r0) & 0xFFFF0000u;
        const unsigned int m1 = __float_as_uint(r1) & 0xFFFF0000u;
        const float q0 = r0 - __uint_as_float(m0);
        const float q1 = r1 - __uint_as_float(m1);
        ph[d] = (h0 >> 16) | h1;
        pm[d] = (m0 >> 16) | m1;
        pl[d] = (__float_as_uint(q0) >> 16) | (__float_as_uint(q1) & 0xFFFF0000u);
        s1 += v0 + v1;
        s2 = fmaf(v0, v0, fmaf(v1, v1, s2));
    }
    AH = as_s8(make_uint4(ph[0], ph[1], ph[2], ph[3]));
    AM = as_s8(make_uint4(pm[0], pm[1], pm[2], pm[3]));
    AL = as_s8(make_uint4(pl[0], pl[1], pl[2], pl[3]));
}

#define MFMA6(ACC, AH, AM, AL, BH, BM, BL)                                        \
    ACC = __builtin_amdgcn_mfma_f32_16x16x32_bf16(AH, as_s8(BH), ACC, 0, 0, 0);   \
    ACC = __builtin_amdgcn_mfma_f32_16x16x32_bf16(AH, as_s8(BM), ACC, 0, 0, 0);   \
    ACC = __builtin_amdgcn_mfma_f32_16x16x32_bf16(AM, as_s8(BH), ACC, 0, 0, 0);   \
    ACC = __builtin_amdgcn_mfma_f32_16x16x32_bf16(AH, as_s8(BL), ACC, 0, 0, 0);   \
    ACC = __builtin_amdgcn_mfma_f32_16x16x32_bf16(AM, as_s8(BM), ACC, 0, 0, 0);   \
    ACC = __builtin_amdgcn_mfma_f32_16x16x32_bf16(AL, as_s8(BH), ACC, 0, 0, 0);

__global__ __launch_bounds__(256, 4)
void router_main(const float* __restrict__ x,
                 const float* __restrict__ ws_ro,       // cs partials (read)
                 const unsigned int* __restrict__ bp,   // packed B frags
                 const float* __restrict__ W2,
                 float* __restrict__ gacc,              // ws base (accum + counter)
                 float* __restrict__ out) {
    // smem plan (floats): ypart[4][32][65] = 8320 | s1l 128 | s2l 128 |
    //                     csgl 64 | csbl 64 | cntl 16 | flag 1
    // w2l  aliases ypart[1] @ +2080 (64x17 = 1088)
    // llds aliases ypart[1] @ +3168 (32x17 = 544)
    __shared__ float smem[8736];
    float* ypart = smem;
    float* s1l   = smem + 8320;
    float* s2l   = smem + 8448;
    float* csgl  = smem + 8576;
    float* csbl  = smem + 8640;
    float* cntl  = smem + 8704;
    float* flagl = smem + 8720;
    float* w2l   = smem + 2080;
    float* llds  = smem + 3168;

    const int t    = threadIdx.x;
    const int wv   = t >> 6;                 // k-range owner
    const int lane = t & 63;
    const int q = lane >> 4, c = lane & 15;
    const int tok0 = blockIdx.x * 32;

    // stage csg/csb (full k-sum of partials) + zero LDS hist
    if (t < 64) {
        float a = 0.f, b = 0.f;
        for (int s = 0; s < 32; ++s) {
            a += ws_ro[CS_F + s * 128 + t];
            b += ws_ro[CS_F + s * 128 + 64 + t];
        }
        csgl[t] = a; csbl[t] = b;
    }
    if (t < 16) cntl[t] = 0.f;

    const float* xr0 = x + (size_t)(tok0 + c) * DDIM + wv * 256 + q * 8;
    const float* xr1 = xr0 + (size_t)16 * DDIM;
    const unsigned int* bpl = bp + lane * 4;

    f32x4 acc0[4] = {{0.f,0.f,0.f,0.f},{0.f,0.f,0.f,0.f},{0.f,0.f,0.f,0.f},{0.f,0.f,0.f,0.f}};
    f32x4 acc1[4] = {{0.f,0.f,0.f,0.f},{0.f,0.f,0.f,0.f},{0.f,0.f,0.f,0.f},{0.f,0.f,0.f,0.f}};
    float s1a = 0.f, s2a = 0.f, s1b = 0.f, s2b = 0.f;

    float4 a00 = *(const float4*)xr0, a01 = *(const float4*)(xr0 + 4);
    float4 a10 = *(const float4*)xr1, a11 = *(const float4*)(xr1 + 4);

    for (int it = 0; it < 8; ++it) {
        const int s = wv * 8 + it;
        const int off = ((it + 1) & 7) * 32;
        // prefetch next k-step A (in flight across this step's compute)
        const float4 n00 = *(const float4*)(xr0 + off);
        const float4 n01 = *(const float4*)(xr0 + off + 4);
        const float4 n10 = *(const float4*)(xr1 + off);
        const float4 n11 = *(const float4*)(xr1 + off + 4);

        short8 AH0, AM0, AL0, AH1, AM1, AL1;
        split8(a00, a01, AH0, AM0, AL0, s1a, s2a);
        split8(a10, a11, AH1, AM1, AL1, s1b, s2b);

#pragma unroll
        for (int n = 0; n < 4; ++n) {
            const uint4 bh = *(const uint4*)(bpl + (s * 4 + n) * 256);
            const uint4 bm = *(const uint4*)(bpl + 32768 + (s * 4 + n) * 256);
            const uint4 bl = *(const uint4*)(bpl + 65536 + (s * 4 + n) * 256);
            MFMA6(acc0[n], AH0, AM0, AL0, bh, bm, bl);
            MFMA6(acc1[n], AH1, AM1, AL1, bh, bm, bl);
        }
        a00 = n00; a01 = n01; a10 = n10; a11 = n11;
    }

    // LN-stat q-reduction (per token, this wave's k-range)
    s1a += __shfl_xor(s1a, 16, 64); s1a += __shfl_xor(s1a, 32, 64);
    s2a += __shfl_xor(s2a, 16, 64); s2a += __shfl_xor(s2a, 32, 64);
    s1b += __shfl_xor(s1b, 16, 64); s1b += __shfl_xor(s1b, 32, 64);
    s2b += __shfl_xor(s2b, 16, 64); s2b += __shfl_xor(s2b, 32, 64);
    if (lane < 16) {
        s1l[wv * 32 + c] = s1a;      s2l[wv * 32 + c] = s2a;
        s1l[wv * 32 + 16 + c] = s1b; s2l[wv * 32 + 16 + c] = s2b;
    }

    // partial acc -> LDS  (C/D: row = q*4+r, col = n*16+c)
#pragma unroll
    for (int n = 0; n < 4; ++n)
#pragma unroll
        for (int r = 0; r < 4; ++r) {
            ypart[wv * 2080 + (q * 4 + r) * 65 + n * 16 + c]        = acc0[n][r];
            ypart[wv * 2080 + (16 + q * 4 + r) * 65 + n * 16 + c]   = acc1[n][r];
        }
    __syncthreads();

    // cross-wave reduce + LN fold + exact GELU. thread: token m, 8 cols
    {
        const int m = t >> 3, cb = (t & 7) * 8;
        const float S1 = s1l[m] + s1l[32 + m] + s1l[64 + m] + s1l[96 + m];
        const float S2 = s2l[m] + s2l[32 + m] + s2l[64 + m] + s2l[96 + m];
        const float mu   = S1 * (1.0f / 1024.0f);
        const float var  = S2 * (1.0f / 1024.0f) - mu * mu;
        const float rstd = 1.0f / sqrtf(var + LN_EPS);
#pragma unroll
        for (int cc = 0; cc < 8; ++cc) {
            const int col = cb + cc;
            const float y = ypart[m * 65 + col] + ypart[2080 + m * 65 + col]
                          + ypart[4160 + m * 65 + col] + ypart[6240 + m * 65 + col];
            const float pre = rstd * (y - mu * csgl[col]) + csbl[col];
            ypart[m * 65 + col] = 0.5f * pre * (1.0f + erff(pre * 0.70710678118654752f));
        }
    }
    __syncthreads();

    // stage W2 -> LDS (aliases ypart[1], now dead)
    {
        const float4 wv4 = *(const float4*)(W2 + t * 4);
        const int j = t >> 2, g = (t & 3) * 4;
        w2l[j * 17 + g + 0] = wv4.x; w2l[j * 17 + g + 1] = wv4.y;
        w2l[j * 17 + g + 2] = wv4.z; w2l[j * 17 + g + 3] = wv4.w;
    }
    __syncthreads();

    // logits: thread -> (token m2, 2 blocks)
    {
        const int m2 = t >> 3, nb0 = (t & 7) * 2;
        float l0 = 0.f, l1 = 0.f;
#pragma unroll
        for (int j = 0; j < 64; ++j) {
            const float h = ypart[m2 * 65 + j];
            l0 = fmaf(h, w2l[j * 17 + nb0], l0);
            l1 = fmaf(h, w2l[j * 17 + nb0 + 1], l1);
        }
        llds[m2 * 17 + nb0]     = l0 * 0.5f;   // /TEMP
        llds[m2 * 17 + nb0 + 1] = l1 * 0.5f;
    }
    __syncthreads();

    // softmax + top-2 + outputs (one thread per token)
    if (t < 32) {
        float p[16];
        float mx = -1e30f;
#pragma unroll
        for (int i = 0; i < NB; ++i) { p[i] = llds[t * 17 + i]; mx = fmaxf(mx, p[i]); }
        float s = 0.f;
#pragma unroll
        for (int i = 0; i < NB; ++i) { p[i] = expf(p[i] - mx); s += p[i]; }
        const float inv = 1.0f / s;
#pragma unroll
        for (int i = 0; i < NB; ++i) { p[i] *= inv; llds[t * 17 + i] = p[i]; }

        float* po = out + (size_t)(tok0 + t) * NB;
#pragma unroll
        for (int u = 0; u < 4; ++u) {
            float4 v; v.x = p[u*4]; v.y = p[u*4+1]; v.z = p[u*4+2]; v.w = p[u*4+3];
            *(float4*)(po + u * 4) = v;
        }

        float b0 = -1.f, b1 = -1.f;
        int i0 = 0, i1 = 0;
#pragma unroll
        for (int i = 0; i < NB; ++i) {
            if (p[i] > b0)      { b1 = b0; i1 = i0; b0 = p[i]; i0 = i; }
            else if (p[i] > b1) { b1 = p[i]; i1 = i; }
        }
        const float wsum = b0 + b1 + 1e-8f;
        out[IDX_OFF + (size_t)(tok0 + t) * 2]     = (float)i0;
        out[IDX_OFF + (size_t)(tok0 + t) * 2 + 1] = (float)i1;
        out[WT_OFF + (size_t)(tok0 + t) * 2]      = b0 / wsum;
        out[WT_OFF + (size_t)(tok0 + t) * 2 + 1]  = b1 / wsum;
        atomicAdd(&cntl[i0], 1.0f);
        atomicAdd(&cntl[i1], 1.0f);
    }
    __syncthreads();

    // device-scope partial accumulation for aux
    if (t < 16) {
        float ps = 0.f;
        for (int m = 0; m < 32; ++m) ps += llds[m * 17 + t];
        atomicAdd(&gacc[16 + t], ps);
        atomicAdd(&gacc[t], cntl[t]);
        __threadfence();
    }
    __syncthreads();
    if (t == 0) {
        __threadfence();
        const unsigned int old = atomicAdd((unsigned int*)(gacc + 32), 1u);
        flagl[0] = (old == 1023u) ? 1.f : 0.f;
    }
    __syncthreads();
    if (flagl[0] != 0.f) {              // block-uniform
        if (t < 32) llds[t] = atomicAdd(&gacc[t], 0.0f);   // coherent read
        __syncthreads();
        if (t == 0) {
            float a = 0.f;
            for (int i = 0; i < NB; ++i) {
                const float f = llds[i] / (65536.0f + 1e-8f);
                const float P = llds[16 + i] * (1.0f / 32768.0f);
                a += f * P;
            }
            out[AUX_OFF] = 16.0f * a;
        }
    }
}

extern "C" void kernel_launch(void* const* d_in, const int* in_sizes, int n_in,
                              void* d_out, int out_size, void* d_ws, size_t ws_size,
                              hipStream_t stream) {
    const float* x     = (const float*)d_in[0];
    const float* gamma = (const float*)d_in[1];
    const float* beta  = (const float*)d_in[2];
    const float* W1    = (const float*)d_in[3];
    const float* W2    = (const float*)d_in[4];
    float* out = (float*)d_out;
    float* ws  = (float*)d_ws;

    hipMemsetAsync(ws, 0, 64 * sizeof(float), stream);   // accum + counter
    pack_kernel<<<32, 256, 0, stream>>>(W1, gamma, beta, ws);
    router_main<<<NTOK / 32, 256, 0, stream>>>(x, ws, (const unsigned int*)(ws + BP_F),
                                               W2, ws, out);
}

// Round 6
// 227.585 us; speedup vs baseline: 1.3473x; 1.2400x over previous
//
#include <hip/hip_runtime.h>
#include <math.h>

typedef __attribute__((ext_vector_type(8))) short short8;
typedef __attribute__((ext_vector_type(4))) float f32x4;

#define NTOK 32768          // B*L
#define DDIM 1024
#define HDIM 64
#define NB 16
#define LN_EPS 1e-5f

#define IDX_OFF ((size_t)NTOK * NB)            // 524288
#define AUX_OFF (IDX_OFF + (size_t)NTOK * 2)   // 589824
#define WT_OFF  (AUX_OFF + 1)                  // 589825

// ws (float) layout:
//   [0:16)  cnt accum   [16:32) Psum accum   [32] completion counter (uint)
//   [64:128)  csg = colsum(gamma*W1)   [128:192) csb = colsum(beta*W1)
//   [4352 : +98304)   B-pack: 3 terms x 32 ksteps x 4 ntiles x 64 lanes x 4 dw
//   [102656 : +16384) per-block partials: 512 blocks x [0:16 cnt | 16:32 Psum]
#define CS_F   64
#define BP_F   4352
#define PART_F 102656

__device__ __forceinline__ short8 as_s8(uint4 u) {
    union { uint4 u; short8 s; } x; x.u = u; return x.s;
}

__device__ __forceinline__ f32x4 ntload4(const float* p) {
    return __builtin_nontemporal_load((const f32x4*)p);
}

// Fused: B-pack (3-term bf16 split of gamma*W1, MFMA B-frag order) + final
// colsums of gamma*W1 / beta*W1 via atomicAdd (ws[CS_F..] pre-zeroed).
__global__ void pack_kernel(const float* __restrict__ W1,
                            const float* __restrict__ gamma,
                            const float* __restrict__ beta,
                            float* __restrict__ ws) {
    __shared__ float sg[4][64];
    __shared__ float sb[4][64];
    const int s = blockIdx.x;           // k-range 32s..32s+31
    const int t = threadIdx.x;          // 256

    {   // cs partials
        const int j = t & 63, p = t >> 6;
        float ag = 0.f, ab = 0.f;
        for (int kk = 0; kk < 8; ++kk) {
            const int k = s * 32 + p * 8 + kk;
            const float w = W1[k * HDIM + j];
            ag += gamma[k] * w;
            ab += beta[k] * w;
        }
        sg[p][j] = ag;
        sb[p][j] = ab;
    }

    {   // B pack
        unsigned int* bp = (unsigned int*)(ws + BP_F);
        const int n = t >> 6;           // n-tile
        const int l = t & 63;           // frag lane
        const int q = l >> 4, c = l & 15;
        const int col = n * 16 + c;
        unsigned int uh[8], um[8], ul[8];
#pragma unroll
        for (int j = 0; j < 8; ++j) {
            const int k = s * 32 + q * 8 + j;
            const float w = gamma[k] * W1[k * HDIM + col];
            const unsigned int hb = __float_as_uint(w) & 0xFFFF0000u;
            const float r = w - __uint_as_float(hb);
            const unsigned int mb = __float_as_uint(r) & 0xFFFF0000u;
            const float r2 = r - __uint_as_float(mb);
            const unsigned int lb = __float_as_uint(r2) & 0xFFFF0000u;
            uh[j] = hb >> 16; um[j] = mb >> 16; ul[j] = lb >> 16;
        }
        const int base = ((s * 4 + n) * 64 + l) * 4;
#pragma unroll
        for (int d = 0; d < 4; ++d) {
            bp[base + d]         = uh[2 * d] | (uh[2 * d + 1] << 16);
            bp[32768 + base + d] = um[2 * d] | (um[2 * d + 1] << 16);
            bp[65536 + base + d] = ul[2 * d] | (ul[2 * d + 1] << 16);
        }
    }
    __syncthreads();
    if (t < 64) {
        atomicAdd(&ws[CS_F + t],      sg[0][t] + sg[1][t] + sg[2][t] + sg[3][t]);
        atomicAdd(&ws[CS_F + 64 + t], sb[0][t] + sb[1][t] + sb[2][t] + sb[3][t]);
    }
}

// 3-term truncated-bf16 split of 8 floats + LN-stat accumulation.
__device__ __forceinline__ void split8(const f32x4 a0, const f32x4 a1,
                                       short8& AH, short8& AM, short8& AL,
                                       float& s1, float& s2) {
    const float v[8] = {a0.x, a0.y, a0.z, a0.w, a1.x, a1.y, a1.z, a1.w};
    unsigned int ph[4], pm[4], pl[4];
#pragma unroll
    for (int d = 0; d < 4; ++d) {
        const float v0 = v[2 * d], v1 = v[2 * d + 1];
        const unsigned int h0 = __float_as_uint(v0) & 0xFFFF0000u;
        const unsigned int h1 = __float_as_uint(v1) & 0xFFFF0000u;
        const float r0 = v0 - __uint_as_float(h0);
        const float r1 = v1 - __uint_as_float(h1);
        const unsigned int m0 = __float_as_uint(r0) & 0xFFFF0000u;
        const unsigned int m1 = __float_as_uint(r1) & 0xFFFF0000u;
        const float q0 = r0 - __uint_as_float(m0);
        const float q1 = r1 - __uint_as_float(m1);
        ph[d] = (h0 >> 16) | h1;
        pm[d] = (m0 >> 16) | m1;
        pl[d] = (__float_as_uint(q0) >> 16) | (__float_as_uint(q1) & 0xFFFF0000u);
        s1 += v0 + v1;
        s2 = fmaf(v0, v0, fmaf(v1, v1, s2));
    }
    AH = as_s8(make_uint4(ph[0], ph[1], ph[2], ph[3]));
    AM = as_s8(make_uint4(pm[0], pm[1], pm[2], pm[3]));
    AL = as_s8(make_uint4(pl[0], pl[1], pl[2], pl[3]));
}

#define MFMA6(ACC, AH, AM, AL, BH, BM, BL)                                        \
    ACC = __builtin_amdgcn_mfma_f32_16x16x32_bf16(AH, as_s8(BH), ACC, 0, 0, 0);   \
    ACC = __builtin_amdgcn_mfma_f32_16x16x32_bf16(AH, as_s8(BM), ACC, 0, 0, 0);   \
    ACC = __builtin_amdgcn_mfma_f32_16x16x32_bf16(AM, as_s8(BH), ACC, 0, 0, 0);   \
    ACC = __builtin_amdgcn_mfma_f32_16x16x32_bf16(AH, as_s8(BL), ACC, 0, 0, 0);   \
    ACC = __builtin_amdgcn_mfma_f32_16x16x32_bf16(AM, as_s8(BM), ACC, 0, 0, 0);   \
    ACC = __builtin_amdgcn_mfma_f32_16x16x32_bf16(AL, as_s8(BH), ACC, 0, 0, 0);

// Block = 64 tokens, 4 waves. Wave w: token-group g=w&1 (32 tokens),
// k-half kh=w>>1 (512 of 1024). Wave does 16 k-steps, 32 tok/wave.
__global__ __launch_bounds__(256, 2)
void router_main(const float* __restrict__ x,
                 const float* __restrict__ ws_ro,       // csg/csb
                 const unsigned int* __restrict__ bp,   // packed B frags
                 const float* __restrict__ W2,
                 float* __restrict__ part,
                 float* __restrict__ out) {
    // smem (floats): ypart[4][32][65]=8320 | s1l[4][32] | s2l[4][32] |
    //                csgl 64 | csbl 64 | cntl 16
    // w2l aliases ypart[2] (+4160), llds aliases ypart[3] (+6240)
    __shared__ float smem[8736];
    float* ypart = smem;
    float* s1l   = smem + 8320;
    float* s2l   = smem + 8448;
    float* csgl  = smem + 8576;
    float* csbl  = smem + 8640;
    float* cntl  = smem + 8704;
    float* w2l   = smem + 4160;
    float* llds  = smem + 6240;

    const int t    = threadIdx.x;
    const int wv   = t >> 6;
    const int lane = t & 63;
    const int q = lane >> 4, c = lane & 15;
    const int g  = wv & 1;                   // token-group
    const int kh = wv >> 1;                  // k-half
    const int tok0 = blockIdx.x * 64;
    const int tokw = tok0 + g * 32;

    if (t < 64) { csgl[t] = ws_ro[CS_F + t]; csbl[t] = ws_ro[CS_F + 64 + t]; }
    if (t < 16) cntl[t] = 0.f;

    const float* xr0 = x + (size_t)(tokw + c) * DDIM + kh * 512 + q * 8;
    const float* xr1 = xr0 + (size_t)16 * DDIM;
    const unsigned int* bpl = bp + lane * 4;

    f32x4 acc0[4] = {{0.f,0.f,0.f,0.f},{0.f,0.f,0.f,0.f},{0.f,0.f,0.f,0.f},{0.f,0.f,0.f,0.f}};
    f32x4 acc1[4] = {{0.f,0.f,0.f,0.f},{0.f,0.f,0.f,0.f},{0.f,0.f,0.f,0.f},{0.f,0.f,0.f,0.f}};
    float s1a = 0.f, s2a = 0.f, s1b = 0.f, s2b = 0.f;

    // A: 2-step software pipeline, nontemporal (protect L2 for B-pack)
    f32x4 a00 = ntload4(xr0),      a01 = ntload4(xr0 + 4);
    f32x4 a10 = ntload4(xr1),      a11 = ntload4(xr1 + 4);
    f32x4 b00 = ntload4(xr0 + 32), b01 = ntload4(xr0 + 36);
    f32x4 b10 = ntload4(xr1 + 32), b11 = ntload4(xr1 + 36);

    for (int it = 0; it < 16; ++it) {
        const int s = kh * 16 + it;

        // B loads first — split8's VALU work below covers their L2 latency
        uint4 bh[4], bm[4], bl[4];
#pragma unroll
        for (int n = 0; n < 4; ++n) {
            bh[n] = *(const uint4*)(bpl + (s * 4 + n) * 256);
            bm[n] = *(const uint4*)(bpl + 32768 + (s * 4 + n) * 256);
            bl[n] = *(const uint4*)(bpl + 65536 + (s * 4 + n) * 256);
        }
        // A prefetch 2 steps ahead
        const int off = ((it + 2) & 15) * 32;
        const f32x4 p00 = ntload4(xr0 + off), p01 = ntload4(xr0 + off + 4);
        const f32x4 p10 = ntload4(xr1 + off), p11 = ntload4(xr1 + off + 4);

        short8 AH0, AM0, AL0, AH1, AM1, AL1;
        split8(a00, a01, AH0, AM0, AL0, s1a, s2a);
        split8(a10, a11, AH1, AM1, AL1, s1b, s2b);

#pragma unroll
        for (int n = 0; n < 4; ++n) {
            MFMA6(acc0[n], AH0, AM0, AL0, bh[n], bm[n], bl[n]);
            MFMA6(acc1[n], AH1, AM1, AL1, bh[n], bm[n], bl[n]);
        }
        a00 = b00; a01 = b01; a10 = b10; a11 = b11;
        b00 = p00; b01 = p01; b10 = p10; b11 = p11;
    }

    // LN-stat q-reduction (per token, this wave's k-half)
    s1a += __shfl_xor(s1a, 16, 64); s1a += __shfl_xor(s1a, 32, 64);
    s2a += __shfl_xor(s2a, 16, 64); s2a += __shfl_xor(s2a, 32, 64);
    s1b += __shfl_xor(s1b, 16, 64); s1b += __shfl_xor(s1b, 32, 64);
    s2b += __shfl_xor(s2b, 16, 64); s2b += __shfl_xor(s2b, 32, 64);
    if (lane < 16) {
        s1l[wv * 32 + c] = s1a;      s2l[wv * 32 + c] = s2a;
        s1l[wv * 32 + 16 + c] = s1b; s2l[wv * 32 + 16 + c] = s2b;
    }

    // partial acc -> LDS  (C/D: row = q*4+r, col = n*16+c)
#pragma unroll
    for (int n = 0; n < 4; ++n)
#pragma unroll
        for (int r = 0; r < 4; ++r) {
            ypart[wv * 2080 + (q * 4 + r) * 65 + n * 16 + c]      = acc0[n][r];
            ypart[wv * 2080 + (16 + q * 4 + r) * 65 + n * 16 + c] = acc1[n][r];
        }
    __syncthreads();

    // k-half combine + LN fold + exact GELU. thread: token m = t>>2, 16 cols
    {
        const int m = t >> 2, cb = (t & 3) * 16;
        const int gg = m >> 5, lm = m & 31;
        const float S1 = s1l[gg * 32 + lm] + s1l[(2 + gg) * 32 + lm];
        const float S2 = s2l[gg * 32 + lm] + s2l[(2 + gg) * 32 + lm];
        const float mu   = S1 * (1.0f / 1024.0f);
        const float var  = S2 * (1.0f / 1024.0f) - mu * mu;
        const float rstd = 1.0f / sqrtf(var + LN_EPS);
#pragma unroll
        for (int cc = 0; cc < 16; ++cc) {
            const int col = cb + cc;
            const float y = ypart[gg * 2080 + lm * 65 + col]
                          + ypart[(2 + gg) * 2080 + lm * 65 + col];
            const float pre = rstd * (y - mu * csgl[col]) + csbl[col];
            ypart[gg * 2080 + lm * 65 + col] =
                0.5f * pre * (1.0f + erff(pre * 0.70710678118654752f));
        }
    }
    __syncthreads();

    // stage W2 -> LDS (aliases ypart[2], dead after GELU)
    {
        const float4 wv4 = *(const float4*)(W2 + t * 4);
        const int j = t >> 2, gq = (t & 3) * 4;
        w2l[j * 17 + gq + 0] = wv4.x; w2l[j * 17 + gq + 1] = wv4.y;
        w2l[j * 17 + gq + 2] = wv4.z; w2l[j * 17 + gq + 3] = wv4.w;
    }
    __syncthreads();

    // logits: thread -> (token m2 = t>>2, 4 blocks)
    {
        const int m2 = t >> 2, nb0 = (t & 3) * 4;
        const int g2 = m2 >> 5, lm2 = m2 & 31;
        const float* hrow = ypart + g2 * 2080 + lm2 * 65;
        float l0 = 0.f, l1 = 0.f, l2 = 0.f, l3 = 0.f;
#pragma unroll
        for (int j = 0; j < 64; ++j) {
            const float h = hrow[j];
            l0 = fmaf(h, w2l[j * 17 + nb0 + 0], l0);
            l1 = fmaf(h, w2l[j * 17 + nb0 + 1], l1);
            l2 = fmaf(h, w2l[j * 17 + nb0 + 2], l2);
            l3 = fmaf(h, w2l[j * 17 + nb0 + 3], l3);
        }
        llds[m2 * 17 + nb0 + 0] = l0 * 0.5f;   // /TEMP
        llds[m2 * 17 + nb0 + 1] = l1 * 0.5f;
        llds[m2 * 17 + nb0 + 2] = l2 * 0.5f;
        llds[m2 * 17 + nb0 + 3] = l3 * 0.5f;
    }
    __syncthreads();

    // softmax + top-2 + outputs (one thread per token)
    if (t < 64) {
        float p[16];
        float mx = -1e30f;
#pragma unroll
        for (int i = 0; i < NB; ++i) { p[i] = llds[t * 17 + i]; mx = fmaxf(mx, p[i]); }
        float s = 0.f;
#pragma unroll
        for (int i = 0; i < NB; ++i) { p[i] = expf(p[i] - mx); s += p[i]; }
        const float inv = 1.0f / s;
#pragma unroll
        for (int i = 0; i < NB; ++i) { p[i] *= inv; llds[t * 17 + i] = p[i]; }

        float* po = out + (size_t)(tok0 + t) * NB;
#pragma unroll
        for (int u = 0; u < 4; ++u) {
            float4 v; v.x = p[u*4]; v.y = p[u*4+1]; v.z = p[u*4+2]; v.w = p[u*4+3];
            *(float4*)(po + u * 4) = v;
        }

        float b0 = -1.f, b1 = -1.f;
        int i0 = 0, i1 = 0;
#pragma unroll
        for (int i = 0; i < NB; ++i) {
            if (p[i] > b0)      { b1 = b0; i1 = i0; b0 = p[i]; i0 = i; }
            else if (p[i] > b1) { b1 = p[i]; i1 = i; }
        }
        const float wsum = b0 + b1 + 1e-8f;
        out[IDX_OFF + (size_t)(tok0 + t) * 2]     = (float)i0;
        out[IDX_OFF + (size_t)(tok0 + t) * 2 + 1] = (float)i1;
        out[WT_OFF + (size_t)(tok0 + t) * 2]      = b0 / wsum;
        out[WT_OFF + (size_t)(tok0 + t) * 2 + 1]  = b1 / wsum;
        atomicAdd(&cntl[i0], 1.0f);
        atomicAdd(&cntl[i1], 1.0f);
    }
    __syncthreads();

    // per-block partials (plain stores; aux kernel reads after dispatch boundary)
    if (t < 16) {
        float ps = 0.f;
        for (int m = 0; m < 64; ++m) ps += llds[m * 17 + t];
        part[(size_t)blockIdx.x * 32 + 16 + t] = ps;
        part[(size_t)blockIdx.x * 32 + t]      = cntl[t];
    }
}

__global__ void aux_kernel(const float* __restrict__ part,
                           float* __restrict__ gacc,
                           float* __restrict__ out) {
    __shared__ float red[8][32];
    __shared__ float flag;
    const int t = threadIdx.x;          // 256
    const int b = blockIdx.x;           // 32 blocks x 16 rows
    const int i = t & 31, rr = t >> 5;  // rr 0..7
    const int r0 = b * 16 + rr;
    red[rr][i] = part[(size_t)r0 * 32 + i] + part[(size_t)(r0 + 8) * 32 + i];
    __syncthreads();
    if (t < 32) {
        float tot = 0.f;
#pragma unroll
        for (int p = 0; p < 8; ++p) tot += red[p][t];
        atomicAdd(&gacc[t], tot);
    }
    __syncthreads();
    if (t == 0) {
        __threadfence();
        const unsigned int old = atomicAdd((unsigned int*)(gacc + 32), 1u);
        flag = (old == 31u) ? 1.f : 0.f;
    }
    __syncthreads();
    if (flag != 0.f) {
        if (t < 32) red[0][t] = atomicAdd(&gacc[t], 0.0f);   // coherent read
        __syncthreads();
        if (t == 0) {
            float a = 0.f;
            for (int k = 0; k < NB; ++k) {
                const float f = red[0][k] / (65536.0f + 1e-8f);
                const float P = red[0][16 + k] * (1.0f / 32768.0f);
                a += f * P;
            }
            out[AUX_OFF] = 16.0f * a;
        }
    }
}

extern "C" void kernel_launch(void* const* d_in, const int* in_sizes, int n_in,
                              void* d_out, int out_size, void* d_ws, size_t ws_size,
                              hipStream_t stream) {
    const float* x     = (const float*)d_in[0];
    const float* gamma = (const float*)d_in[1];
    const float* beta  = (const float*)d_in[2];
    const float* W1    = (const float*)d_in[3];
    const float* W2    = (const float*)d_in[4];
    float* out = (float*)d_out;
    float* ws  = (float*)d_ws;

    (void)hipMemsetAsync(ws, 0, 192 * sizeof(float), stream);  // accums + counter + cs
    pack_kernel<<<32, 256, 0, stream>>>(W1, gamma, beta, ws);
    router_main<<<NTOK / 64, 256, 0, stream>>>(x, ws, (const unsigned int*)(ws + BP_F),
                                               W2, ws + PART_F, out);
    aux_kernel<<<32, 256, 0, stream>>>(ws + PART_F, ws, out);
}